// Round 19
// baseline (537.989 us; speedup 1.0000x reference)
//
#include <hip/hip_runtime.h>
#include <cstdint>

#define NN 50000
#define DD 128
#define EE 600000
#define NBK 49          // row buckets of 1024
#define BCAP 14336      // sort2 LDS edge capacity (mean 12288, sigma~110)

typedef __attribute__((ext_vector_type(8))) short bf16x8;
typedef __attribute__((ext_vector_type(4))) float f32x4;

__device__ __forceinline__ float sigmoid_f(float x) {
    return 1.0f / (1.0f + __expf(-x));
}
__device__ __forceinline__ float tanh_f(float x) {
    float e = __expf(-2.0f * fabsf(x));
    float t = (1.0f - e) / (1.0f + e);
    return copysignf(t, x);
}
__device__ __forceinline__ unsigned short bf16_rn(float v) {
    unsigned u = __float_as_uint(v);
    u = u + 0x7fffu + ((u >> 16) & 1u);
    return (unsigned short)(u >> 16);
}
__device__ __forceinline__ float bf16_tf(unsigned short h) {
    return __uint_as_float(((unsigned)h) << 16);
}

// ---- weight packing into MFMA B-panels (unchanged) ------------------------
__global__ __launch_bounds__(256) void pack_w_kernel(const float* __restrict__ wx,
                                                     const float* __restrict__ wh,
                                                     unsigned short* __restrict__ Wp) {
    int idx = blockIdx.x * 256 + threadIdx.x;   // 24*512*32
    if (idx >= 24 * 512 * 32) return;
    int k8 = idx & 31;
    int n = (idx >> 5) & 511;
    int kb = idx >> 14;
    int grp = kb >> 2;
    int k = (kb & 3) * 32 + k8;
    float v = 0.f;
    if (grp < 3) {
        if (n < 384) v = wx[n * 128 + k];
    } else {
        if (n < 256) v = wh[n * 128 + k];
        else if (n >= 384) v = wh[(n - 128) * 128 + k];
    }
    unsigned short hi = bf16_rn(v);
    bool lo = (grp == 2) || (grp == 5);
    Wp[idx] = lo ? bf16_rn(v - bf16_tf(hi)) : hi;
}

// ---- CSR build (unchanged) ------------------------------------------------

__global__ __launch_bounds__(256) void bhist_kernel(const int* __restrict__ rows,
                                                    int* __restrict__ bcnt4) {
    __shared__ int lc[NBK];
    const int tid = threadIdx.x;
    const int k = blockIdx.y;
    const int e0 = blockIdx.x * 2048;
    if (tid < NBK) lc[tid] = 0;
    __syncthreads();
    #pragma unroll
    for (int i = 0; i < 8; ++i) {
        int e = e0 + i * 256 + tid;
        if (e < EE) atomicAdd(&lc[rows[(size_t)k * EE + e] >> 10], 1);
    }
    __syncthreads();
    if (tid < NBK && lc[tid]) atomicAdd(&bcnt4[k * NBK + tid], lc[tid]);
}

__global__ __launch_bounds__(64) void bscan_kernel(const int* __restrict__ bcnt4,
                                                   int* __restrict__ bbase4,
                                                   int* __restrict__ bcur4) {
    int k = threadIdx.x;
    if (k < 4) {
        int run = 0;
        for (int b = 0; b < NBK; ++b) {
            bbase4[k * NBK + b] = run;
            bcur4[k * NBK + b] = run;
            run += bcnt4[k * NBK + b];
        }
    }
}

__global__ __launch_bounds__(256) void bscat_kernel(const int* __restrict__ rows,
                                                    const int* __restrict__ cols,
                                                    const float* __restrict__ vals,
                                                    int* __restrict__ bcur4,
                                                    int2* __restrict__ st2) {
    __shared__ int lcnt[4][NBK];
    __shared__ int sstart4[4][NBK];
    __shared__ int sstart_b[NBK];
    __shared__ int gbase[NBK];
    __shared__ int ltot;
    __shared__ int sw0[2048];
    __shared__ int sw1[2048];
    __shared__ unsigned char sbk[2048];

    const int tid = threadIdx.x;
    const int w = tid >> 6;
    const int k = blockIdx.y;
    const int e0 = blockIdx.x * 2048;

    if (tid < NBK) { lcnt[0][tid] = 0; lcnt[1][tid] = 0; lcnt[2][tid] = 0; lcnt[3][tid] = 0; }
    __syncthreads();

    int eb[8], er[8], ew0[8], ew1[8];
    #pragma unroll
    for (int i = 0; i < 8; ++i) {
        int e = e0 + i * 256 + tid;
        eb[i] = -1;
        if (e < EE) {
            size_t off = (size_t)k * EE + e;
            int r = rows[off];
            int b = r >> 10;
            eb[i] = b;
            er[i] = atomicAdd(&lcnt[w][b], 1);
            ew0[i] = ((r & 1023) << 17) | cols[off];
            ew1[i] = __float_as_int(vals[off]);
        }
    }
    __syncthreads();
    if (tid == 0) {
        int run = 0;
        for (int b = 0; b < NBK; ++b) {
            sstart_b[b] = run;
            #pragma unroll
            for (int q = 0; q < 4; ++q) { sstart4[q][b] = run; run += lcnt[q][b]; }
        }
        ltot = run;
    }
    __syncthreads();
    if (tid < NBK) {
        int n = (sstart4[3][tid] + lcnt[3][tid]) - sstart_b[tid];
        if (n) gbase[tid] = atomicAdd(&bcur4[k * NBK + tid], n);
    }
    __syncthreads();
    #pragma unroll
    for (int i = 0; i < 8; ++i) {
        if (eb[i] >= 0) {
            int slot = sstart4[w][eb[i]] + er[i];
            sw0[slot] = ew0[i];
            sw1[slot] = ew1[i];
            sbk[slot] = (unsigned char)eb[i];
        }
    }
    __syncthreads();
    const int tot = ltot;
    #pragma unroll
    for (int i = 0; i < 8; ++i) {
        int slot = i * 256 + tid;
        if (slot < tot) {
            int b = sbk[slot];
            int pos = gbase[b] + (slot - sstart_b[b]);
            st2[(size_t)k * EE + pos] = make_int2(sw0[slot], sw1[slot]);
        }
    }
}

__global__ __launch_bounds__(1024, 1) void sort2_kernel(const int2* __restrict__ st2,
                                                        const int* __restrict__ bbase4,
                                                        const int* __restrict__ bcnt4,
                                                        int* __restrict__ row_ptr4,
                                                        int2* __restrict__ epair4) {
    __shared__ int cnt[1024];
    __shared__ int cur[1024];
    __shared__ int2 obuf[BCAP];

    const int tid = threadIdx.x;
    const int b = blockIdx.x;
    const int k = blockIdx.y;
    const int base = bbase4[k * NBK + b];
    const int n = bcnt4[k * NBK + b];

    cnt[tid] = 0;
    __syncthreads();
    for (int i = tid; i < n; i += 1024)
        atomicAdd(&cnt[st2[(size_t)k * EE + base + i].x >> 17], 1);
    __syncthreads();

    int v = cnt[tid];
    cur[tid] = v;
    __syncthreads();
    for (int d = 1; d < 1024; d <<= 1) {
        int t = (tid >= d) ? cur[tid - d] : 0;
        __syncthreads();
        cur[tid] += t;
        __syncthreads();
    }
    int excl = cur[tid] - v;

    int grow = b * 1024 + tid;
    if (grow <= NN) row_ptr4[k * (NN + 1) + grow] = base + excl;

    cur[tid] = excl;
    __syncthreads();
    for (int i = tid; i < n; i += 1024) {
        int2 p = st2[(size_t)k * EE + base + i];
        int rl = p.x >> 17;
        int pos = atomicAdd(&cur[rl], 1);
        if (pos < BCAP) obuf[pos] = make_int2(p.x & 0x1FFFF, p.y);
    }
    __syncthreads();
    for (int i = tid; i < n; i += 1024)
        epair4[(size_t)k * EE + base + i] = obuf[i];
}

// ---- SpMM gather (unchanged) ----------------------------------------------
__global__ __launch_bounds__(256) void gather_kernel(const float* __restrict__ x,
                                                     const int* __restrict__ row_ptr,
                                                     const int2* __restrict__ epair,
                                                     unsigned short* __restrict__ Rh,
                                                     unsigned short* __restrict__ Rl) {
    const int tid = threadIdx.x;
    const int row = blockIdx.x * 8 + (tid >> 5);
    const int d0 = (tid & 31) * 4;
    const int start = row_ptr[row];
    const int end = row_ptr[row + 1];
    float4 a0 = make_float4(0.f, 0.f, 0.f, 0.f);
    float4 a1 = a0, a2 = a0, a3 = a0;
    int e = start;
    for (; e + 3 < end; e += 4) {
        int2 p0 = epair[e], p1 = epair[e + 1], p2 = epair[e + 2], p3 = epair[e + 3];
        float4 x0 = *reinterpret_cast<const float4*>(x + (size_t)p0.x * DD + d0);
        float4 x1 = *reinterpret_cast<const float4*>(x + (size_t)p1.x * DD + d0);
        float4 x2 = *reinterpret_cast<const float4*>(x + (size_t)p2.x * DD + d0);
        float4 x3 = *reinterpret_cast<const float4*>(x + (size_t)p3.x * DD + d0);
        float v0 = __int_as_float(p0.y), v1 = __int_as_float(p1.y);
        float v2 = __int_as_float(p2.y), v3 = __int_as_float(p3.y);
        a0.x += v0 * x0.x; a0.y += v0 * x0.y; a0.z += v0 * x0.z; a0.w += v0 * x0.w;
        a1.x += v1 * x1.x; a1.y += v1 * x1.y; a1.z += v1 * x1.z; a1.w += v1 * x1.w;
        a2.x += v2 * x2.x; a2.y += v2 * x2.y; a2.z += v2 * x2.z; a2.w += v2 * x2.w;
        a3.x += v3 * x3.x; a3.y += v3 * x3.y; a3.z += v3 * x3.z; a3.w += v3 * x3.w;
    }
    for (; e < end; ++e) {
        int2 p0 = epair[e];
        float v0 = __int_as_float(p0.y);
        float4 x0 = *reinterpret_cast<const float4*>(x + (size_t)p0.x * DD + d0);
        a0.x += v0 * x0.x; a0.y += v0 * x0.y; a0.z += v0 * x0.z; a0.w += v0 * x0.w;
    }
    float o[4];
    o[0] = fmaxf((a0.x + a1.x) + (a2.x + a3.x), 0.f);
    o[1] = fmaxf((a0.y + a1.y) + (a2.y + a3.y), 0.f);
    o[2] = fmaxf((a0.z + a1.z) + (a2.z + a3.z), 0.f);
    o[3] = fmaxf((a0.w + a1.w) + (a2.w + a3.w), 0.f);
    ushort4 vh, vl;
    unsigned short h0 = bf16_rn(o[0]); vh.x = h0; vl.x = bf16_rn(o[0] - bf16_tf(h0));
    unsigned short h1 = bf16_rn(o[1]); vh.y = h1; vl.y = bf16_rn(o[1] - bf16_tf(h1));
    unsigned short h2 = bf16_rn(o[2]); vh.z = h2; vl.z = bf16_rn(o[2] - bf16_tf(h2));
    unsigned short h3 = bf16_rn(o[3]); vh.w = h3; vl.w = bf16_rn(o[3] - bf16_tf(h3));
    *reinterpret_cast<ushort4*>(Rh + (size_t)row * DD + d0) = vh;
    *reinterpret_cast<ushort4*>(Rl + (size_t)row * DD + d0) = vl;
}

// ---- MFMA split-bf16 dual-GEMM + fused GRU --------------------------------
// 512 thr = 8 waves; wave = 64 rows x 16 j across 3 live gate-blocks.
// Burst staging (R18). Epilogue: each hy packed + stored IMMEDIATELY to the
// idle Hstage LDS (no cross-barrier registers -> no spill), then one barrier,
// then FULL 512B row streaming stores (kills partial-line write RMW).
template <bool FIRST, bool LAST>
__global__ __launch_bounds__(512, 4)
void gemm_gru_kernel(const unsigned short* __restrict__ Rh,
                     const unsigned short* __restrict__ Rl,
                     unsigned int* __restrict__ Hpk,
                     float* __restrict__ hout,
                     const unsigned short* __restrict__ Wp,
                     const float* __restrict__ bx,
                     const float* __restrict__ bh) {
    __shared__ unsigned short sA[2 * 64 * 128];   // 32 KB (hi, lo slabs)
    __shared__ unsigned int Hstage[64 * 128];     // 32 KB packed H / out-stage

    const int tid = threadIdx.x;
    const int row0 = blockIdx.x * 64;
    const int lane = tid & 63;
    const int w = tid >> 6;        // 0..7
    const int g = lane >> 4;       // 0..3
    const int m16 = lane & 15;

    f32x4 acc[4][4];               // [gate][mt]
    #pragma unroll
    for (int G = 0; G < 4; ++G)
        #pragma unroll
        for (int mt = 0; mt < 4; ++mt)
            acc[G][mt] = (f32x4){0.f, 0.f, 0.f, 0.f};

    // ---- burst staging: Rh/Rl -> slabs (swizzled), Hpk -> Hstage (linear)
    {
        #pragma unroll
        for (int it = 0; it < 4; ++it) {
            int arr = it >> 1;
            int idx = (it & 1) * 512 + tid;   // 0..1023
            int row = idx >> 4;
            int slot = idx & 15;
            int grow = row0 + row;
            uint4 v = make_uint4(0, 0, 0, 0);
            if (grow < NN) {
                const unsigned short* src = arr ? Rl : Rh;
                v = *reinterpret_cast<const uint4*>(src + (size_t)grow * 128 + slot * 8);
            }
            int sw = slot ^ (row & 7);
            *reinterpret_cast<uint4*>(sA + ((arr * 64 + row) * 16 + sw) * 8) = v;
        }
        if (!FIRST) {
            #pragma unroll
            for (int it = 0; it < 4; ++it) {
                int idx = it * 512 + tid;     // 0..2047
                int row = idx >> 5;           // 0..63
                int j0 = (idx & 31) * 4;
                int grow = row0 + row;
                uint4 v = make_uint4(0, 0, 0, 0);
                if (grow < NN)
                    v = *reinterpret_cast<const uint4*>(Hpk + (size_t)grow * 128 + j0);
                *reinterpret_cast<uint4*>(&Hstage[row * 128 + j0]) = v;
            }
        }
    }
    __syncthreads();

    auto do_kb = [&](int kb, int arr, int G0, int G1, int G2) {
        int kq = kb & 3;
        bf16x8 bfr[3];
        const int Gs[3] = {G0, G1, G2};
        #pragma unroll
        for (int i = 0; i < 3; ++i) {
            int n = Gs[i] * 128 + w * 16 + m16;
            bfr[i] = *reinterpret_cast<const bf16x8*>(
                Wp + ((size_t)(kb * 512 + n)) * 32 + g * 8);
        }
        bf16x8 afr[4];
        #pragma unroll
        for (int mt = 0; mt < 4; ++mt) {
            int row = mt * 16 + m16;
            int sw = (kq * 4 + g) ^ (row & 7);
            afr[mt] = *reinterpret_cast<const bf16x8*>(
                sA + ((arr * 64 + row) * 16 + sw) * 8);
        }
        #pragma unroll
        for (int mt = 0; mt < 4; ++mt) {
            acc[G0][mt] = __builtin_amdgcn_mfma_f32_16x16x32_bf16(afr[mt], bfr[0], acc[G0][mt], 0, 0, 0);
            acc[G1][mt] = __builtin_amdgcn_mfma_f32_16x16x32_bf16(afr[mt], bfr[1], acc[G1][mt], 0, 0, 0);
            acc[G2][mt] = __builtin_amdgcn_mfma_f32_16x16x32_bf16(afr[mt], bfr[2], acc[G2][mt], 0, 0, 0);
        }
    };

    // phase A: x-side, kb 0-11 (grp 0:Rh*Whi, 1:Rl*Whi, 2:Rh*Wlo)
    for (int kb = 0; kb < 12; ++kb) {
        int grp = kb >> 2;
        do_kb(kb, (grp == 1) ? 1 : 0, 0, 1, 2);
    }

    // phase B: h-side, kb 12-23 (grp 3:Hh*Whi, 4:Hl*Whi, 5:Hh*Wlo)
    if (!FIRST) {
        __syncthreads();    // done reading phase-A slabs
        // LDS->LDS de-interleave Hstage -> slabs
        #pragma unroll
        for (int it = 0; it < 4; ++it) {
            int idx = it * 512 + tid;
            int row = idx >> 5;
            int j0 = (idx & 31) * 4;
            uint4 v = *reinterpret_cast<const uint4*>(&Hstage[row * 128 + j0]);
            ushort4 hh = make_ushort4(v.x & 0xFFFF, v.y & 0xFFFF, v.z & 0xFFFF, v.w & 0xFFFF);
            ushort4 hl = make_ushort4(v.x >> 16, v.y >> 16, v.z >> 16, v.w >> 16);
            int sw = (j0 >> 3) ^ (row & 7);
            int b0 = ((0 * 64 + row) * 16 + sw) * 8 + (j0 & 7);
            int b1 = ((1 * 64 + row) * 16 + sw) * 8 + (j0 & 7);
            *reinterpret_cast<ushort4*>(sA + b0) = hh;
            *reinterpret_cast<ushort4*>(sA + b1) = hl;
        }
        __syncthreads();
        for (int kb = 12; kb < 24; ++kb) {
            int grp = kb >> 2;
            do_kb(kb, (grp == 4) ? 1 : 0, 0, 1, 3);
        }
    }

    // ---- GRU epilogue: compute hy, pack, store IMMEDIATELY to Hstage LDS
    // (ho reads sA; Hstage is idle here; each (row,j) written by one thread)
    {
        int j = w * 16 + m16;
        float bxr = bx[j], bxi = bx[128 + j], bxn = bx[256 + j];
        float bhr = bh[j], bhi = bh[128 + j], bhn = bh[256 + j];
        #pragma unroll
        for (int mt = 0; mt < 4; ++mt) {
            #pragma unroll
            for (int ii = 0; ii < 4; ++ii) {
                int lrow = mt * 16 + g * 4 + ii;
                float rr = acc[0][mt][ii] + bxr + bhr;
                float ri = acc[1][mt][ii] + bxi + bhi;
                float rin = acc[2][mt][ii] + bxn;
                float rhn = bhn;
                float ho = 0.f;
                if (!FIRST) {
                    rhn += acc[3][mt][ii];
                    int sw = (j >> 3) ^ (lrow & 7);
                    int bi = (lrow * 16 + sw) * 8 + (j & 7);
                    ho = bf16_tf(sA[bi]) + bf16_tf(sA[64 * 128 + bi]);
                }
                float rg = sigmoid_f(rr);
                float ig = sigmoid_f(ri);
                float ng = tanh_f(rin + rg * rhn);
                float hy = ng + ig * (ho - ng);
                unsigned val;
                if (LAST) {
                    val = __float_as_uint(hy);
                } else {
                    unsigned short hh = bf16_rn(hy);
                    unsigned short hl = bf16_rn(hy - bf16_tf(hh));
                    val = (unsigned)hh | ((unsigned)hl << 16);
                }
                Hstage[lrow * 128 + j] = val;
            }
        }
    }
    __syncthreads();
    // ---- stream FULL 512B rows to global (each row written once)
    {
        unsigned int* dst = LAST ? reinterpret_cast<unsigned int*>(hout) : Hpk;
        #pragma unroll
        for (int it = 0; it < 4; ++it) {
            int idx = it * 512 + tid;     // 0..2047
            int row = idx >> 5;           // 0..63
            int c4 = (idx & 31) * 4;
            int grow = row0 + row;
            if (grow < NN) {
                uint4 v = *reinterpret_cast<const uint4*>(&Hstage[row * 128 + c4]);
                *reinterpret_cast<uint4*>(dst + (size_t)grow * 128 + c4) = v;
            }
        }
    }
}

// LayerNorm (unchanged)
__global__ __launch_bounds__(256) void ln_kernel(float* __restrict__ h,
                                                 const float* __restrict__ g,
                                                 const float* __restrict__ b) {
    int tid = threadIdx.x;
    int lane = tid & 31;
    int rl = tid >> 5;
    int row = blockIdx.x * 8 + rl;
    if (row >= NN) return;
    float4 v = *reinterpret_cast<const float4*>(h + (size_t)row * DD + lane * 4);
    float s = v.x + v.y + v.z + v.w;
    #pragma unroll
    for (int m = 16; m >= 1; m >>= 1) s += __shfl_xor(s, m, 64);
    float mean = s * (1.0f / DD);
    float dx = v.x - mean, dy = v.y - mean, dz = v.z - mean, dw = v.w - mean;
    float q = dx * dx + dy * dy + dz * dz + dw * dw;
    #pragma unroll
    for (int m = 16; m >= 1; m >>= 1) q += __shfl_xor(q, m, 64);
    float var = q * (1.0f / DD);
    float inv = 1.0f / sqrtf(var + 1e-5f);
    float4 gv = *reinterpret_cast<const float4*>(g + lane * 4);
    float4 bv = *reinterpret_cast<const float4*>(b + lane * 4);
    float4 o;
    o.x = dx * inv * gv.x + bv.x;
    o.y = dy * inv * gv.y + bv.y;
    o.z = dz * inv * gv.z + bv.z;
    o.w = dw * inv * gv.w + bv.w;
    *reinterpret_cast<float4*>(h + (size_t)row * DD + lane * 4) = o;
}

static inline size_t align_up(size_t v, size_t a) { return (v + a - 1) & ~(a - 1); }

extern "C" void kernel_launch(void* const* d_in, const int* in_sizes, int n_in,
                              void* d_out, int out_size, void* d_ws, size_t ws_size,
                              hipStream_t stream) {
    const float* x    = (const float*)d_in[0];
    const float* vals = (const float*)d_in[1];
    const float* wx   = (const float*)d_in[2];
    const float* bx   = (const float*)d_in[3];
    const float* wh   = (const float*)d_in[4];
    const float* bh   = (const float*)d_in[5];
    const float* lng  = (const float*)d_in[6];
    const float* lnb  = (const float*)d_in[7];
    const int* rows   = (const int*)d_in[8];
    const int* cols   = (const int*)d_in[9];

    float* hout = (float*)d_out;

    size_t off = 0;
    char* wsb = (char*)d_ws;
    unsigned short* Rh = (unsigned short*)(wsb + off); off = align_up(off + (size_t)NN * DD * 2, 256);
    unsigned short* Rl = (unsigned short*)(wsb + off); off = align_up(off + (size_t)NN * DD * 2, 256);
    unsigned int* Hpk = (unsigned int*)(wsb + off);    off = align_up(off + (size_t)NN * DD * 4, 256);
    unsigned short* Wp = (unsigned short*)(wsb + off); off = align_up(off + (size_t)24 * 512 * 32 * 2, 256);
    int* row_ptr4 = (int*)(wsb + off);  off = align_up(off + (size_t)4 * (NN + 1) * 4, 256);
    int2* epair4 = (int2*)(wsb + off);  off = align_up(off + (size_t)4 * EE * 8, 256);
    int* bcnt4 = (int*)(wsb + off);     off = align_up(off + (size_t)4 * NBK * 4, 256);
    int* bbase4 = (int*)(wsb + off);    off = align_up(off + (size_t)4 * NBK * 4, 256);
    int* bcur4 = (int*)(wsb + off);     off = align_up(off + (size_t)4 * NBK * 4, 256);
    // staging aliases Rh/Rl (19.2 MB < 25.6 MB): CSR build completes before
    // the first gather writes Rh/Rl (stream-ordered)
    int2* st2 = (int2*)wsb;

    (void)in_sizes; (void)n_in; (void)out_size; (void)ws_size;

    pack_w_kernel<<<1536, 256, 0, stream>>>(wx, wh, Wp);

    hipMemsetAsync(bcnt4, 0, (size_t)4 * NBK * sizeof(int), stream);
    dim3 e2grid((EE + 2047) / 2048, 4);          // 293 x 4
    bhist_kernel<<<e2grid, 256, 0, stream>>>(rows, bcnt4);
    bscan_kernel<<<1, 64, 0, stream>>>(bcnt4, bbase4, bcur4);
    bscat_kernel<<<e2grid, 256, 0, stream>>>(rows, cols, vals, bcur4, st2);
    dim3 sgrid(NBK, 4);                          // 49 x 4
    sort2_kernel<<<sgrid, 1024, 0, stream>>>(st2, bbase4, bcnt4, row_ptr4, epair4);

    const int ggrid = NN / 8;                 // 6250
    const int mgrid = (NN + 63) / 64;         // 782

    for (int s = 0; s < 4; ++s) {
        int k = 3 - s;  // adj_list reversed
        gather_kernel<<<ggrid, 256, 0, stream>>>(
            x, row_ptr4 + (size_t)k * (NN + 1), epair4 + (size_t)k * EE, Rh, Rl);
        if (s == 0)
            gemm_gru_kernel<true, false><<<mgrid, 512, 0, stream>>>(
                Rh, Rl, Hpk, hout, Wp, bx, bh);
        else if (s < 3)
            gemm_gru_kernel<false, false><<<mgrid, 512, 0, stream>>>(
                Rh, Rl, Hpk, hout, Wp, bx, bh);
        else
            gemm_gru_kernel<false, true><<<mgrid, 512, 0, stream>>>(
                Rh, Rl, Hpk, hout, Wp, bx, bh);
    }

    ln_kernel<<<(NN + 7) / 8, 256, 0, stream>>>(hout, lng, lnb);
}

// Round 20
// 441.633 us; speedup vs baseline: 1.2182x; 1.2182x over previous
//
#include <hip/hip_runtime.h>
#include <cstdint>

#define NN 50000
#define DD 128
#define EE 600000
#define NBK 49          // row buckets of 1024
#define BCAP 14336      // sort2 LDS edge capacity (mean 12288, sigma~110)

typedef __attribute__((ext_vector_type(8))) short bf16x8;
typedef __attribute__((ext_vector_type(4))) float f32x4;

__device__ __forceinline__ float sigmoid_f(float x) {
    return 1.0f / (1.0f + __expf(-x));
}
__device__ __forceinline__ float tanh_f(float x) {
    float e = __expf(-2.0f * fabsf(x));
    float t = (1.0f - e) / (1.0f + e);
    return copysignf(t, x);
}
__device__ __forceinline__ unsigned short bf16_rn(float v) {
    unsigned u = __float_as_uint(v);
    u = u + 0x7fffu + ((u >> 16) & 1u);
    return (unsigned short)(u >> 16);
}
__device__ __forceinline__ float bf16_tf(unsigned short h) {
    return __uint_as_float(((unsigned)h) << 16);
}

// ---- weight packing into MFMA B-panels ------------------------------------
__global__ __launch_bounds__(256) void pack_w_kernel(const float* __restrict__ wx,
                                                     const float* __restrict__ wh,
                                                     unsigned short* __restrict__ Wp) {
    int idx = blockIdx.x * 256 + threadIdx.x;   // 24*512*32
    if (idx >= 24 * 512 * 32) return;
    int k8 = idx & 31;
    int n = (idx >> 5) & 511;
    int kb = idx >> 14;
    int grp = kb >> 2;
    int k = (kb & 3) * 32 + k8;
    float v = 0.f;
    if (grp < 3) {
        if (n < 384) v = wx[n * 128 + k];
    } else {
        if (n < 256) v = wh[n * 128 + k];
        else if (n >= 384) v = wh[(n - 128) * 128 + k];
    }
    unsigned short hi = bf16_rn(v);
    bool lo = (grp == 2) || (grp == 5);
    Wp[idx] = lo ? bf16_rn(v - bf16_tf(hi)) : hi;
}

// ---- CSR build ------------------------------------------------------------

__global__ __launch_bounds__(256) void bhist_kernel(const int* __restrict__ rows,
                                                    int* __restrict__ bcnt4) {
    __shared__ int lc[NBK];
    const int tid = threadIdx.x;
    const int k = blockIdx.y;
    const int e0 = blockIdx.x * 2048;
    if (tid < NBK) lc[tid] = 0;
    __syncthreads();
    #pragma unroll
    for (int i = 0; i < 8; ++i) {
        int e = e0 + i * 256 + tid;
        if (e < EE) atomicAdd(&lc[rows[(size_t)k * EE + e] >> 10], 1);
    }
    __syncthreads();
    if (tid < NBK && lc[tid]) atomicAdd(&bcnt4[k * NBK + tid], lc[tid]);
}

__global__ __launch_bounds__(64) void bscan_kernel(const int* __restrict__ bcnt4,
                                                   int* __restrict__ bbase4,
                                                   int* __restrict__ bcur4) {
    int k = threadIdx.x;
    if (k < 4) {
        int run = 0;
        for (int b = 0; b < NBK; ++b) {
            bbase4[k * NBK + b] = run;
            bcur4[k * NBK + b] = run;
            run += bcnt4[k * NBK + b];
        }
    }
}

__global__ __launch_bounds__(256) void bscat_kernel(const int* __restrict__ rows,
                                                    const int* __restrict__ cols,
                                                    const float* __restrict__ vals,
                                                    int* __restrict__ bcur4,
                                                    int2* __restrict__ st2) {
    __shared__ int lcnt[4][NBK];
    __shared__ int sstart4[4][NBK];
    __shared__ int sstart_b[NBK];
    __shared__ int gbase[NBK];
    __shared__ int ltot;
    __shared__ int sw0[2048];
    __shared__ int sw1[2048];
    __shared__ unsigned char sbk[2048];

    const int tid = threadIdx.x;
    const int w = tid >> 6;
    const int k = blockIdx.y;
    const int e0 = blockIdx.x * 2048;

    if (tid < NBK) { lcnt[0][tid] = 0; lcnt[1][tid] = 0; lcnt[2][tid] = 0; lcnt[3][tid] = 0; }
    __syncthreads();

    int eb[8], er[8], ew0[8], ew1[8];
    #pragma unroll
    for (int i = 0; i < 8; ++i) {
        int e = e0 + i * 256 + tid;
        eb[i] = -1;
        if (e < EE) {
            size_t off = (size_t)k * EE + e;
            int r = rows[off];
            int b = r >> 10;
            eb[i] = b;
            er[i] = atomicAdd(&lcnt[w][b], 1);
            ew0[i] = ((r & 1023) << 17) | cols[off];
            ew1[i] = __float_as_int(vals[off]);
        }
    }
    __syncthreads();
    if (tid == 0) {
        int run = 0;
        for (int b = 0; b < NBK; ++b) {
            sstart_b[b] = run;
            #pragma unroll
            for (int q = 0; q < 4; ++q) { sstart4[q][b] = run; run += lcnt[q][b]; }
        }
        ltot = run;
    }
    __syncthreads();
    if (tid < NBK) {
        int n = (sstart4[3][tid] + lcnt[3][tid]) - sstart_b[tid];
        if (n) gbase[tid] = atomicAdd(&bcur4[k * NBK + tid], n);
    }
    __syncthreads();
    #pragma unroll
    for (int i = 0; i < 8; ++i) {
        if (eb[i] >= 0) {
            int slot = sstart4[w][eb[i]] + er[i];
            sw0[slot] = ew0[i];
            sw1[slot] = ew1[i];
            sbk[slot] = (unsigned char)eb[i];
        }
    }
    __syncthreads();
    const int tot = ltot;
    #pragma unroll
    for (int i = 0; i < 8; ++i) {
        int slot = i * 256 + tid;
        if (slot < tot) {
            int b = sbk[slot];
            int pos = gbase[b] + (slot - sstart_b[b]);
            st2[(size_t)k * EE + pos] = make_int2(sw0[slot], sw1[slot]);
        }
    }
}

__global__ __launch_bounds__(1024, 1) void sort2_kernel(const int2* __restrict__ st2,
                                                        const int* __restrict__ bbase4,
                                                        const int* __restrict__ bcnt4,
                                                        int* __restrict__ row_ptr4,
                                                        int2* __restrict__ epair4) {
    __shared__ int cnt[1024];
    __shared__ int cur[1024];
    __shared__ int2 obuf[BCAP];

    const int tid = threadIdx.x;
    const int b = blockIdx.x;
    const int k = blockIdx.y;
    const int base = bbase4[k * NBK + b];
    const int n = bcnt4[k * NBK + b];

    cnt[tid] = 0;
    __syncthreads();
    for (int i = tid; i < n; i += 1024)
        atomicAdd(&cnt[st2[(size_t)k * EE + base + i].x >> 17], 1);
    __syncthreads();

    int v = cnt[tid];
    cur[tid] = v;
    __syncthreads();
    for (int d = 1; d < 1024; d <<= 1) {
        int t = (tid >= d) ? cur[tid - d] : 0;
        __syncthreads();
        cur[tid] += t;
        __syncthreads();
    }
    int excl = cur[tid] - v;

    int grow = b * 1024 + tid;
    if (grow <= NN) row_ptr4[k * (NN + 1) + grow] = base + excl;

    cur[tid] = excl;
    __syncthreads();
    for (int i = tid; i < n; i += 1024) {
        int2 p = st2[(size_t)k * EE + base + i];
        int rl = p.x >> 17;
        int pos = atomicAdd(&cur[rl], 1);
        if (pos < BCAP) obuf[pos] = make_int2(p.x & 0x1FFFF, p.y);
    }
    __syncthreads();
    for (int i = tid; i < n; i += 1024)
        epair4[(size_t)k * EE + base + i] = obuf[i];
}

// ---- SpMM gather ----------------------------------------------------------
__global__ __launch_bounds__(256) void gather_kernel(const float* __restrict__ x,
                                                     const int* __restrict__ row_ptr,
                                                     const int2* __restrict__ epair,
                                                     unsigned short* __restrict__ Rh,
                                                     unsigned short* __restrict__ Rl) {
    const int tid = threadIdx.x;
    const int row = blockIdx.x * 8 + (tid >> 5);
    const int d0 = (tid & 31) * 4;
    const int start = row_ptr[row];
    const int end = row_ptr[row + 1];
    float4 a0 = make_float4(0.f, 0.f, 0.f, 0.f);
    float4 a1 = a0, a2 = a0, a3 = a0;
    int e = start;
    for (; e + 3 < end; e += 4) {
        int2 p0 = epair[e], p1 = epair[e + 1], p2 = epair[e + 2], p3 = epair[e + 3];
        float4 x0 = *reinterpret_cast<const float4*>(x + (size_t)p0.x * DD + d0);
        float4 x1 = *reinterpret_cast<const float4*>(x + (size_t)p1.x * DD + d0);
        float4 x2 = *reinterpret_cast<const float4*>(x + (size_t)p2.x * DD + d0);
        float4 x3 = *reinterpret_cast<const float4*>(x + (size_t)p3.x * DD + d0);
        float v0 = __int_as_float(p0.y), v1 = __int_as_float(p1.y);
        float v2 = __int_as_float(p2.y), v3 = __int_as_float(p3.y);
        a0.x += v0 * x0.x; a0.y += v0 * x0.y; a0.z += v0 * x0.z; a0.w += v0 * x0.w;
        a1.x += v1 * x1.x; a1.y += v1 * x1.y; a1.z += v1 * x1.z; a1.w += v1 * x1.w;
        a2.x += v2 * x2.x; a2.y += v2 * x2.y; a2.z += v2 * x2.z; a2.w += v2 * x2.w;
        a3.x += v3 * x3.x; a3.y += v3 * x3.y; a3.z += v3 * x3.z; a3.w += v3 * x3.w;
    }
    for (; e < end; ++e) {
        int2 p0 = epair[e];
        float v0 = __int_as_float(p0.y);
        float4 x0 = *reinterpret_cast<const float4*>(x + (size_t)p0.x * DD + d0);
        a0.x += v0 * x0.x; a0.y += v0 * x0.y; a0.z += v0 * x0.z; a0.w += v0 * x0.w;
    }
    float o[4];
    o[0] = fmaxf((a0.x + a1.x) + (a2.x + a3.x), 0.f);
    o[1] = fmaxf((a0.y + a1.y) + (a2.y + a3.y), 0.f);
    o[2] = fmaxf((a0.z + a1.z) + (a2.z + a3.z), 0.f);
    o[3] = fmaxf((a0.w + a1.w) + (a2.w + a3.w), 0.f);
    ushort4 vh, vl;
    unsigned short h0 = bf16_rn(o[0]); vh.x = h0; vl.x = bf16_rn(o[0] - bf16_tf(h0));
    unsigned short h1 = bf16_rn(o[1]); vh.y = h1; vl.y = bf16_rn(o[1] - bf16_tf(h1));
    unsigned short h2 = bf16_rn(o[2]); vh.z = h2; vl.z = bf16_rn(o[2] - bf16_tf(h2));
    unsigned short h3 = bf16_rn(o[3]); vh.w = h3; vl.w = bf16_rn(o[3] - bf16_tf(h3));
    *reinterpret_cast<ushort4*>(Rh + (size_t)row * DD + d0) = vh;
    *reinterpret_cast<ushort4*>(Rl + (size_t)row * DD + d0) = vl;
}

// ---- MFMA split-bf16 dual-GEMM + fused GRU (R16 structure + setprio) ------
// 512 thr = 8 waves; wave = 64 rows x 16 j across 3 live gate-blocks.
// Phase A: stage Rh/Rl, kb 0-11; phase B: re-stage Hpk mid-kernel, kb 12-23.
// Epilogue: scattered per-lane stores (R16-proven best). s_setprio(1) wraps
// the MFMA cluster: co-resident blocks are at DIFFERENT phases -> arbitration
// favors MFMA-issuing waves (T5 applicability regime, m191).
template <bool FIRST, bool LAST>
__global__ __launch_bounds__(512, 4)
void gemm_gru_kernel(const unsigned short* __restrict__ Rh,
                     const unsigned short* __restrict__ Rl,
                     unsigned int* __restrict__ Hpk,
                     float* __restrict__ hout,
                     const unsigned short* __restrict__ Wp,
                     const float* __restrict__ bx,
                     const float* __restrict__ bh) {
    __shared__ unsigned short sA[2 * 64 * 128];   // 32 KB (hi, lo slabs)

    const int tid = threadIdx.x;
    const int row0 = blockIdx.x * 64;
    const int lane = tid & 63;
    const int w = tid >> 6;        // 0..7
    const int g = lane >> 4;       // 0..3
    const int m16 = lane & 15;

    f32x4 acc[4][4];               // [gate][mt]
    #pragma unroll
    for (int G = 0; G < 4; ++G)
        #pragma unroll
        for (int mt = 0; mt < 4; ++mt)
            acc[G][mt] = (f32x4){0.f, 0.f, 0.f, 0.f};

    // stage A: Rh/Rl slabs, swizzled slot ^= row&7
    auto stageA = [&]() {
        #pragma unroll
        for (int it = 0; it < 4; ++it) {
            int arr = it >> 1;
            int idx = (it & 1) * 512 + tid;   // 0..1023
            int row = idx >> 4;
            int slot = idx & 15;
            int grow = row0 + row;
            uint4 v = make_uint4(0, 0, 0, 0);
            if (grow < NN) {
                const unsigned short* src = arr ? Rl : Rh;
                v = *reinterpret_cast<const uint4*>(src + (size_t)grow * 128 + slot * 8);
            }
            int sw = slot ^ (row & 7);
            *reinterpret_cast<uint4*>(sA + ((arr * 64 + row) * 16 + sw) * 8) = v;
        }
    };

    // stage B: packed Hpk -> de-interleave into hi/lo slabs
    auto stageH = [&]() {
        #pragma unroll
        for (int it = 0; it < 4; ++it) {
            int idx = it * 512 + tid;         // 0..2047
            int row = idx >> 5;               // 0..63
            int j0 = (idx & 31) * 4;
            int grow = row0 + row;
            uint4 v = make_uint4(0, 0, 0, 0);
            if (grow < NN)
                v = *reinterpret_cast<const uint4*>(Hpk + (size_t)grow * 128 + j0);
            ushort4 hh = make_ushort4(v.x & 0xFFFF, v.y & 0xFFFF, v.z & 0xFFFF, v.w & 0xFFFF);
            ushort4 hl = make_ushort4(v.x >> 16, v.y >> 16, v.z >> 16, v.w >> 16);
            int sw = (j0 >> 3) ^ (row & 7);
            int b0 = ((0 * 64 + row) * 16 + sw) * 8 + (j0 & 7);
            int b1 = ((1 * 64 + row) * 16 + sw) * 8 + (j0 & 7);
            *reinterpret_cast<ushort4*>(sA + b0) = hh;
            *reinterpret_cast<ushort4*>(sA + b1) = hl;
        }
    };

    auto do_kb = [&](int kb, int arr, int G0, int G1, int G2) {
        int kq = kb & 3;
        bf16x8 bfr[3];
        const int Gs[3] = {G0, G1, G2};
        #pragma unroll
        for (int i = 0; i < 3; ++i) {
            int n = Gs[i] * 128 + w * 16 + m16;
            bfr[i] = *reinterpret_cast<const bf16x8*>(
                Wp + ((size_t)(kb * 512 + n)) * 32 + g * 8);
        }
        bf16x8 afr[4];
        #pragma unroll
        for (int mt = 0; mt < 4; ++mt) {
            int row = mt * 16 + m16;
            int sw = (kq * 4 + g) ^ (row & 7);
            afr[mt] = *reinterpret_cast<const bf16x8*>(
                sA + ((arr * 64 + row) * 16 + sw) * 8);
        }
        __builtin_amdgcn_s_setprio(1);
        #pragma unroll
        for (int mt = 0; mt < 4; ++mt) {
            acc[G0][mt] = __builtin_amdgcn_mfma_f32_16x16x32_bf16(afr[mt], bfr[0], acc[G0][mt], 0, 0, 0);
            acc[G1][mt] = __builtin_amdgcn_mfma_f32_16x16x32_bf16(afr[mt], bfr[1], acc[G1][mt], 0, 0, 0);
            acc[G2][mt] = __builtin_amdgcn_mfma_f32_16x16x32_bf16(afr[mt], bfr[2], acc[G2][mt], 0, 0, 0);
        }
        __builtin_amdgcn_s_setprio(0);
    };

    // phase A: x-side, kb 0-11 (grp 0:Rh*Whi, 1:Rl*Whi, 2:Rh*Wlo)
    stageA();
    __syncthreads();
    for (int kb = 0; kb < 12; ++kb) {
        int grp = kb >> 2;
        do_kb(kb, (grp == 1) ? 1 : 0, 0, 1, 2);
    }

    // phase B: h-side, kb 12-23 (grp 3:Hh*Whi, 4:Hl*Whi, 5:Hh*Wlo)
    if (!FIRST) {
        __syncthreads();
        stageH();
        __syncthreads();
        for (int kb = 12; kb < 24; ++kb) {
            int grp = kb >> 2;
            do_kb(kb, (grp == 4) ? 1 : 0, 0, 1, 3);
        }
    }

    // ---- GRU epilogue (R16): C layout col=m16, row=g*4+ii (m89)
    {
        int j = w * 16 + m16;
        float bxr = bx[j], bxi = bx[128 + j], bxn = bx[256 + j];
        float bhr = bh[j], bhi = bh[128 + j], bhn = bh[256 + j];
        #pragma unroll
        for (int mt = 0; mt < 4; ++mt) {
            #pragma unroll
            for (int ii = 0; ii < 4; ++ii) {
                int lrow = mt * 16 + g * 4 + ii;
                int grow = row0 + lrow;
                if (grow >= NN) continue;
                float rr = acc[0][mt][ii] + bxr + bhr;
                float ri = acc[1][mt][ii] + bxi + bhi;
                float rin = acc[2][mt][ii] + bxn;
                float rhn = bhn;
                float ho = 0.f;
                if (!FIRST) {
                    rhn += acc[3][mt][ii];
                    int sw = (j >> 3) ^ (lrow & 7);
                    int bi = (lrow * 16 + sw) * 8 + (j & 7);
                    ho = bf16_tf(sA[bi]) + bf16_tf(sA[64 * 128 + bi]);
                }
                float rg = sigmoid_f(rr);
                float ig = sigmoid_f(ri);
                float ng = tanh_f(rin + rg * rhn);
                float hy = ng + ig * (ho - ng);
                if (LAST) {
                    hout[(size_t)grow * 128 + j] = hy;
                } else {
                    unsigned short hh = bf16_rn(hy);
                    unsigned short hl = bf16_rn(hy - bf16_tf(hh));
                    Hpk[(size_t)grow * 128 + j] = (unsigned)hh | ((unsigned)hl << 16);
                }
            }
        }
    }
}

// LayerNorm
__global__ __launch_bounds__(256) void ln_kernel(float* __restrict__ h,
                                                 const float* __restrict__ g,
                                                 const float* __restrict__ b) {
    int tid = threadIdx.x;
    int lane = tid & 31;
    int rl = tid >> 5;
    int row = blockIdx.x * 8 + rl;
    if (row >= NN) return;
    float4 v = *reinterpret_cast<const float4*>(h + (size_t)row * DD + lane * 4);
    float s = v.x + v.y + v.z + v.w;
    #pragma unroll
    for (int m = 16; m >= 1; m >>= 1) s += __shfl_xor(s, m, 64);
    float mean = s * (1.0f / DD);
    float dx = v.x - mean, dy = v.y - mean, dz = v.z - mean, dw = v.w - mean;
    float q = dx * dx + dy * dy + dz * dz + dw * dw;
    #pragma unroll
    for (int m = 16; m >= 1; m >>= 1) q += __shfl_xor(q, m, 64);
    float var = q * (1.0f / DD);
    float inv = 1.0f / sqrtf(var + 1e-5f);
    float4 gv = *reinterpret_cast<const float4*>(g + lane * 4);
    float4 bv = *reinterpret_cast<const float4*>(b + lane * 4);
    float4 o;
    o.x = dx * inv * gv.x + bv.x;
    o.y = dy * inv * gv.y + bv.y;
    o.z = dz * inv * gv.z + bv.z;
    o.w = dw * inv * gv.w + bv.w;
    *reinterpret_cast<float4*>(h + (size_t)row * DD + lane * 4) = o;
}

static inline size_t align_up(size_t v, size_t a) { return (v + a - 1) & ~(a - 1); }

extern "C" void kernel_launch(void* const* d_in, const int* in_sizes, int n_in,
                              void* d_out, int out_size, void* d_ws, size_t ws_size,
                              hipStream_t stream) {
    const float* x    = (const float*)d_in[0];
    const float* vals = (const float*)d_in[1];
    const float* wx   = (const float*)d_in[2];
    const float* bx   = (const float*)d_in[3];
    const float* wh   = (const float*)d_in[4];
    const float* bh   = (const float*)d_in[5];
    const float* lng  = (const float*)d_in[6];
    const float* lnb  = (const float*)d_in[7];
    const int* rows   = (const int*)d_in[8];
    const int* cols   = (const int*)d_in[9];

    float* hout = (float*)d_out;

    size_t off = 0;
    char* wsb = (char*)d_ws;
    unsigned short* Rh = (unsigned short*)(wsb + off); off = align_up(off + (size_t)NN * DD * 2, 256);
    unsigned short* Rl = (unsigned short*)(wsb + off); off = align_up(off + (size_t)NN * DD * 2, 256);
    unsigned int* Hpk = (unsigned int*)(wsb + off);    off = align_up(off + (size_t)NN * DD * 4, 256);
    unsigned short* Wp = (unsigned short*)(wsb + off); off = align_up(off + (size_t)24 * 512 * 32 * 2, 256);
    int* row_ptr4 = (int*)(wsb + off);  off = align_up(off + (size_t)4 * (NN + 1) * 4, 256);
    int2* epair4 = (int2*)(wsb + off);  off = align_up(off + (size_t)4 * EE * 8, 256);
    int* bcnt4 = (int*)(wsb + off);     off = align_up(off + (size_t)4 * NBK * 4, 256);
    int* bbase4 = (int*)(wsb + off);    off = align_up(off + (size_t)4 * NBK * 4, 256);
    int* bcur4 = (int*)(wsb + off);     off = align_up(off + (size_t)4 * NBK * 4, 256);
    // staging aliases Rh/Rl (19.2 MB < 25.6 MB): CSR build completes before
    // the first gather writes Rh/Rl (stream-ordered)
    int2* st2 = (int2*)wsb;

    (void)in_sizes; (void)n_in; (void)out_size; (void)ws_size;

    pack_w_kernel<<<1536, 256, 0, stream>>>(wx, wh, Wp);

    hipMemsetAsync(bcnt4, 0, (size_t)4 * NBK * sizeof(int), stream);
    dim3 e2grid((EE + 2047) / 2048, 4);          // 293 x 4
    bhist_kernel<<<e2grid, 256, 0, stream>>>(rows, bcnt4);
    bscan_kernel<<<1, 64, 0, stream>>>(bcnt4, bbase4, bcur4);
    bscat_kernel<<<e2grid, 256, 0, stream>>>(rows, cols, vals, bcur4, st2);
    dim3 sgrid(NBK, 4);                          // 49 x 4
    sort2_kernel<<<sgrid, 1024, 0, stream>>>(st2, bbase4, bcnt4, row_ptr4, epair4);

    const int ggrid = NN / 8;                 // 6250
    const int mgrid = (NN + 63) / 64;         // 782

    for (int s = 0; s < 4; ++s) {
        int k = 3 - s;  // adj_list reversed
        gather_kernel<<<ggrid, 256, 0, stream>>>(
            x, row_ptr4 + (size_t)k * (NN + 1), epair4 + (size_t)k * EE, Rh, Rl);
        if (s == 0)
            gemm_gru_kernel<true, false><<<mgrid, 512, 0, stream>>>(
                Rh, Rl, Hpk, hout, Wp, bx, bh);
        else if (s < 3)
            gemm_gru_kernel<false, false><<<mgrid, 512, 0, stream>>>(
                Rh, Rl, Hpk, hout, Wp, bx, bh);
        else
            gemm_gru_kernel<false, true><<<mgrid, 512, 0, stream>>>(
                Rh, Rl, Hpk, hout, Wp, bx, bh);
    }

    ln_kernel<<<(NN + 7) / 8, 256, 0, stream>>>(hout, lng, lnb);
}

// Round 21
// 412.452 us; speedup vs baseline: 1.3044x; 1.0708x over previous
//
#include <hip/hip_runtime.h>
#include <cstdint>

#define NN 50000
#define DD 128
#define EE 600000
#define NBK 49          // row buckets of 1024
#define BCAP 14336      // sort2 LDS edge capacity (mean 12288, sigma~110)

typedef __attribute__((ext_vector_type(8))) short bf16x8;
typedef __attribute__((ext_vector_type(4))) float f32x4;

__device__ __forceinline__ float sigmoid_f(float x) {
    return 1.0f / (1.0f + __expf(-x));
}
__device__ __forceinline__ float tanh_f(float x) {
    float e = __expf(-2.0f * fabsf(x));
    float t = (1.0f - e) / (1.0f + e);
    return copysignf(t, x);
}
__device__ __forceinline__ unsigned short bf16_rn(float v) {
    unsigned u = __float_as_uint(v);
    u = u + 0x7fffu + ((u >> 16) & 1u);
    return (unsigned short)(u >> 16);
}
__device__ __forceinline__ float bf16_tf(unsigned short h) {
    return __uint_as_float(((unsigned)h) << 16);
}

// ---- weight packing into MFMA B-panels ------------------------------------
__global__ __launch_bounds__(256) void pack_w_kernel(const float* __restrict__ wx,
                                                     const float* __restrict__ wh,
                                                     unsigned short* __restrict__ Wp) {
    int idx = blockIdx.x * 256 + threadIdx.x;   // 24*512*32
    if (idx >= 24 * 512 * 32) return;
    int k8 = idx & 31;
    int n = (idx >> 5) & 511;
    int kb = idx >> 14;
    int grp = kb >> 2;
    int k = (kb & 3) * 32 + k8;
    float v = 0.f;
    if (grp < 3) {
        if (n < 384) v = wx[n * 128 + k];
    } else {
        if (n < 256) v = wh[n * 128 + k];
        else if (n >= 384) v = wh[(n - 128) * 128 + k];
    }
    unsigned short hi = bf16_rn(v);
    bool lo = (grp == 2) || (grp == 5);
    Wp[idx] = lo ? bf16_rn(v - bf16_tf(hi)) : hi;
}

// ---- CSR build ------------------------------------------------------------

__global__ __launch_bounds__(256) void bhist_kernel(const int* __restrict__ rows,
                                                    int* __restrict__ bcnt4) {
    __shared__ int lc[NBK];
    const int tid = threadIdx.x;
    const int k = blockIdx.y;
    const int e0 = blockIdx.x * 2048;
    if (tid < NBK) lc[tid] = 0;
    __syncthreads();
    #pragma unroll
    for (int i = 0; i < 8; ++i) {
        int e = e0 + i * 256 + tid;
        if (e < EE) atomicAdd(&lc[rows[(size_t)k * EE + e] >> 10], 1);
    }
    __syncthreads();
    if (tid < NBK && lc[tid]) atomicAdd(&bcnt4[k * NBK + tid], lc[tid]);
}

__global__ __launch_bounds__(64) void bscan_kernel(const int* __restrict__ bcnt4,
                                                   int* __restrict__ bbase4,
                                                   int* __restrict__ bcur4) {
    int k = threadIdx.x;
    if (k < 4) {
        int run = 0;
        for (int b = 0; b < NBK; ++b) {
            bbase4[k * NBK + b] = run;
            bcur4[k * NBK + b] = run;
            run += bcnt4[k * NBK + b];
        }
    }
}

__global__ __launch_bounds__(256) void bscat_kernel(const int* __restrict__ rows,
                                                    const int* __restrict__ cols,
                                                    const float* __restrict__ vals,
                                                    int* __restrict__ bcur4,
                                                    int2* __restrict__ st2) {
    __shared__ int lcnt[4][NBK];
    __shared__ int sstart4[4][NBK];
    __shared__ int sstart_b[NBK];
    __shared__ int gbase[NBK];
    __shared__ int ltot;
    __shared__ int sw0[2048];
    __shared__ int sw1[2048];
    __shared__ unsigned char sbk[2048];

    const int tid = threadIdx.x;
    const int w = tid >> 6;
    const int k = blockIdx.y;
    const int e0 = blockIdx.x * 2048;

    if (tid < NBK) { lcnt[0][tid] = 0; lcnt[1][tid] = 0; lcnt[2][tid] = 0; lcnt[3][tid] = 0; }
    __syncthreads();

    int eb[8], er[8], ew0[8], ew1[8];
    #pragma unroll
    for (int i = 0; i < 8; ++i) {
        int e = e0 + i * 256 + tid;
        eb[i] = -1;
        if (e < EE) {
            size_t off = (size_t)k * EE + e;
            int r = rows[off];
            int b = r >> 10;
            eb[i] = b;
            er[i] = atomicAdd(&lcnt[w][b], 1);
            ew0[i] = ((r & 1023) << 17) | cols[off];
            ew1[i] = __float_as_int(vals[off]);
        }
    }
    __syncthreads();
    if (tid == 0) {
        int run = 0;
        for (int b = 0; b < NBK; ++b) {
            sstart_b[b] = run;
            #pragma unroll
            for (int q = 0; q < 4; ++q) { sstart4[q][b] = run; run += lcnt[q][b]; }
        }
        ltot = run;
    }
    __syncthreads();
    if (tid < NBK) {
        int n = (sstart4[3][tid] + lcnt[3][tid]) - sstart_b[tid];
        if (n) gbase[tid] = atomicAdd(&bcur4[k * NBK + tid], n);
    }
    __syncthreads();
    #pragma unroll
    for (int i = 0; i < 8; ++i) {
        if (eb[i] >= 0) {
            int slot = sstart4[w][eb[i]] + er[i];
            sw0[slot] = ew0[i];
            sw1[slot] = ew1[i];
            sbk[slot] = (unsigned char)eb[i];
        }
    }
    __syncthreads();
    const int tot = ltot;
    #pragma unroll
    for (int i = 0; i < 8; ++i) {
        int slot = i * 256 + tid;
        if (slot < tot) {
            int b = sbk[slot];
            int pos = gbase[b] + (slot - sstart_b[b]);
            st2[(size_t)k * EE + pos] = make_int2(sw0[slot], sw1[slot]);
        }
    }
}

__global__ __launch_bounds__(1024, 1) void sort2_kernel(const int2* __restrict__ st2,
                                                        const int* __restrict__ bbase4,
                                                        const int* __restrict__ bcnt4,
                                                        int* __restrict__ row_ptr4,
                                                        int2* __restrict__ epair4) {
    __shared__ int cnt[1024];
    __shared__ int cur[1024];
    __shared__ int2 obuf[BCAP];

    const int tid = threadIdx.x;
    const int b = blockIdx.x;
    const int k = blockIdx.y;
    const int base = bbase4[k * NBK + b];
    const int n = bcnt4[k * NBK + b];

    cnt[tid] = 0;
    __syncthreads();
    for (int i = tid; i < n; i += 1024)
        atomicAdd(&cnt[st2[(size_t)k * EE + base + i].x >> 17], 1);
    __syncthreads();

    int v = cnt[tid];
    cur[tid] = v;
    __syncthreads();
    for (int d = 1; d < 1024; d <<= 1) {
        int t = (tid >= d) ? cur[tid - d] : 0;
        __syncthreads();
        cur[tid] += t;
        __syncthreads();
    }
    int excl = cur[tid] - v;

    int grow = b * 1024 + tid;
    if (grow <= NN) row_ptr4[k * (NN + 1) + grow] = base + excl;

    cur[tid] = excl;
    __syncthreads();
    for (int i = tid; i < n; i += 1024) {
        int2 p = st2[(size_t)k * EE + base + i];
        int rl = p.x >> 17;
        int pos = atomicAdd(&cur[rl], 1);
        if (pos < BCAP) obuf[pos] = make_int2(p.x & 0x1FFFF, p.y);
    }
    __syncthreads();
    for (int i = tid; i < n; i += 1024)
        epair4[(size_t)k * EE + base + i] = obuf[i];
}

// ---- SpMM gather ----------------------------------------------------------
__global__ __launch_bounds__(256) void gather_kernel(const float* __restrict__ x,
                                                     const int* __restrict__ row_ptr,
                                                     const int2* __restrict__ epair,
                                                     unsigned short* __restrict__ Rh,
                                                     unsigned short* __restrict__ Rl) {
    const int tid = threadIdx.x;
    const int row = blockIdx.x * 8 + (tid >> 5);
    const int d0 = (tid & 31) * 4;
    const int start = row_ptr[row];
    const int end = row_ptr[row + 1];
    float4 a0 = make_float4(0.f, 0.f, 0.f, 0.f);
    float4 a1 = a0, a2 = a0, a3 = a0;
    int e = start;
    for (; e + 3 < end; e += 4) {
        int2 p0 = epair[e], p1 = epair[e + 1], p2 = epair[e + 2], p3 = epair[e + 3];
        float4 x0 = *reinterpret_cast<const float4*>(x + (size_t)p0.x * DD + d0);
        float4 x1 = *reinterpret_cast<const float4*>(x + (size_t)p1.x * DD + d0);
        float4 x2 = *reinterpret_cast<const float4*>(x + (size_t)p2.x * DD + d0);
        float4 x3 = *reinterpret_cast<const float4*>(x + (size_t)p3.x * DD + d0);
        float v0 = __int_as_float(p0.y), v1 = __int_as_float(p1.y);
        float v2 = __int_as_float(p2.y), v3 = __int_as_float(p3.y);
        a0.x += v0 * x0.x; a0.y += v0 * x0.y; a0.z += v0 * x0.z; a0.w += v0 * x0.w;
        a1.x += v1 * x1.x; a1.y += v1 * x1.y; a1.z += v1 * x1.z; a1.w += v1 * x1.w;
        a2.x += v2 * x2.x; a2.y += v2 * x2.y; a2.z += v2 * x2.z; a2.w += v2 * x2.w;
        a3.x += v3 * x3.x; a3.y += v3 * x3.y; a3.z += v3 * x3.z; a3.w += v3 * x3.w;
    }
    for (; e < end; ++e) {
        int2 p0 = epair[e];
        float v0 = __int_as_float(p0.y);
        float4 x0 = *reinterpret_cast<const float4*>(x + (size_t)p0.x * DD + d0);
        a0.x += v0 * x0.x; a0.y += v0 * x0.y; a0.z += v0 * x0.z; a0.w += v0 * x0.w;
    }
    float o[4];
    o[0] = fmaxf((a0.x + a1.x) + (a2.x + a3.x), 0.f);
    o[1] = fmaxf((a0.y + a1.y) + (a2.y + a3.y), 0.f);
    o[2] = fmaxf((a0.z + a1.z) + (a2.z + a3.z), 0.f);
    o[3] = fmaxf((a0.w + a1.w) + (a2.w + a3.w), 0.f);
    ushort4 vh, vl;
    unsigned short h0 = bf16_rn(o[0]); vh.x = h0; vl.x = bf16_rn(o[0] - bf16_tf(h0));
    unsigned short h1 = bf16_rn(o[1]); vh.y = h1; vl.y = bf16_rn(o[1] - bf16_tf(h1));
    unsigned short h2 = bf16_rn(o[2]); vh.z = h2; vl.z = bf16_rn(o[2] - bf16_tf(h2));
    unsigned short h3 = bf16_rn(o[3]); vh.w = h3; vl.w = bf16_rn(o[3] - bf16_tf(h3));
    *reinterpret_cast<ushort4*>(Rh + (size_t)row * DD + d0) = vh;
    *reinterpret_cast<ushort4*>(Rl + (size_t)row * DD + d0) = vl;
}

// ---- MFMA split-bf16 dual-GEMM + fused GRU (R20 + hi-weight dedup) --------
// kq-major schedule: per kq issue (grp_hi x Ahi), (grp_hi x Alo), (grp_lo x Ahi)
// with the duplicate hi-weight loads REDIRECTED to the same address ->
// back-to-back identical loads hit L1; Wp L2 traffic -33%.
template <bool FIRST, bool LAST>
__global__ __launch_bounds__(512, 4)
void gemm_gru_kernel(const unsigned short* __restrict__ Rh,
                     const unsigned short* __restrict__ Rl,
                     unsigned int* __restrict__ Hpk,
                     float* __restrict__ hout,
                     const unsigned short* __restrict__ Wp,
                     const float* __restrict__ bx,
                     const float* __restrict__ bh) {
    __shared__ unsigned short sA[2 * 64 * 128];   // 32 KB (hi, lo slabs)

    const int tid = threadIdx.x;
    const int row0 = blockIdx.x * 64;
    const int lane = tid & 63;
    const int w = tid >> 6;        // 0..7
    const int g = lane >> 4;       // 0..3
    const int m16 = lane & 15;

    f32x4 acc[4][4];               // [gate][mt]
    #pragma unroll
    for (int G = 0; G < 4; ++G)
        #pragma unroll
        for (int mt = 0; mt < 4; ++mt)
            acc[G][mt] = (f32x4){0.f, 0.f, 0.f, 0.f};

    // stage A: Rh/Rl slabs, swizzled slot ^= row&7
    auto stageA = [&]() {
        #pragma unroll
        for (int it = 0; it < 4; ++it) {
            int arr = it >> 1;
            int idx = (it & 1) * 512 + tid;   // 0..1023
            int row = idx >> 4;
            int slot = idx & 15;
            int grow = row0 + row;
            uint4 v = make_uint4(0, 0, 0, 0);
            if (grow < NN) {
                const unsigned short* src = arr ? Rl : Rh;
                v = *reinterpret_cast<const uint4*>(src + (size_t)grow * 128 + slot * 8);
            }
            int sw = slot ^ (row & 7);
            *reinterpret_cast<uint4*>(sA + ((arr * 64 + row) * 16 + sw) * 8) = v;
        }
    };

    // stage B: packed Hpk -> de-interleave into hi/lo slabs
    auto stageH = [&]() {
        #pragma unroll
        for (int it = 0; it < 4; ++it) {
            int idx = it * 512 + tid;         // 0..2047
            int row = idx >> 5;               // 0..63
            int j0 = (idx & 31) * 4;
            int grow = row0 + row;
            uint4 v = make_uint4(0, 0, 0, 0);
            if (grow < NN)
                v = *reinterpret_cast<const uint4*>(Hpk + (size_t)grow * 128 + j0);
            ushort4 hh = make_ushort4(v.x & 0xFFFF, v.y & 0xFFFF, v.z & 0xFFFF, v.w & 0xFFFF);
            ushort4 hl = make_ushort4(v.x >> 16, v.y >> 16, v.z >> 16, v.w >> 16);
            int sw = (j0 >> 3) ^ (row & 7);
            int b0 = ((0 * 64 + row) * 16 + sw) * 8 + (j0 & 7);
            int b1 = ((1 * 64 + row) * 16 + sw) * 8 + (j0 & 7);
            *reinterpret_cast<ushort4*>(sA + b0) = hh;
            *reinterpret_cast<ushort4*>(sA + b1) = hl;
        }
    };

    // one 12-MFMA cluster: B-fragments from Wp panel kbW, A-fragments from
    // slab arr at k-quad kq (slab swizzle depends on kq only)
    auto do_kb2 = [&](int kbW, int kq, int arr, int G0, int G1, int G2) {
        bf16x8 bfr[3];
        const int Gs[3] = {G0, G1, G2};
        #pragma unroll
        for (int i = 0; i < 3; ++i) {
            int n = Gs[i] * 128 + w * 16 + m16;
            bfr[i] = *reinterpret_cast<const bf16x8*>(
                Wp + ((size_t)(kbW * 512 + n)) * 32 + g * 8);
        }
        bf16x8 afr[4];
        #pragma unroll
        for (int mt = 0; mt < 4; ++mt) {
            int row = mt * 16 + m16;
            int sw = (kq * 4 + g) ^ (row & 7);
            afr[mt] = *reinterpret_cast<const bf16x8*>(
                sA + ((arr * 64 + row) * 16 + sw) * 8);
        }
        __builtin_amdgcn_s_setprio(1);
        #pragma unroll
        for (int mt = 0; mt < 4; ++mt) {
            acc[G0][mt] = __builtin_amdgcn_mfma_f32_16x16x32_bf16(afr[mt], bfr[0], acc[G0][mt], 0, 0, 0);
            acc[G1][mt] = __builtin_amdgcn_mfma_f32_16x16x32_bf16(afr[mt], bfr[1], acc[G1][mt], 0, 0, 0);
            acc[G2][mt] = __builtin_amdgcn_mfma_f32_16x16x32_bf16(afr[mt], bfr[2], acc[G2][mt], 0, 0, 0);
        }
        __builtin_amdgcn_s_setprio(0);
    };

    // phase A: x-side, kq-major. Whi panel = kb[0+kq] (used twice, 2nd hits L1),
    // Wlo panel = kb[8+kq]. Slabs: arr0=Rh, arr1=Rl.
    stageA();
    __syncthreads();
    for (int kq = 0; kq < 4; ++kq) {
        do_kb2(kq,     kq, 0, 0, 1, 2);   // Rh x Whi
        do_kb2(kq,     kq, 1, 0, 1, 2);   // Rl x Whi (same Wp addresses -> L1)
        do_kb2(8 + kq, kq, 0, 0, 1, 2);   // Rh x Wlo
    }

    // phase B: h-side. Whi_h = kb[12+kq] (x2), Wlo_h = kb[20+kq].
    if (!FIRST) {
        __syncthreads();
        stageH();
        __syncthreads();
        for (int kq = 0; kq < 4; ++kq) {
            do_kb2(12 + kq, kq, 0, 0, 1, 3);   // Hh x Whi_h
            do_kb2(12 + kq, kq, 1, 0, 1, 3);   // Hl x Whi_h (L1 hit)
            do_kb2(20 + kq, kq, 0, 0, 1, 3);   // Hh x Wlo_h
        }
    }

    // ---- GRU epilogue (R16/R20): C layout col=m16, row=g*4+ii (m89)
    {
        int j = w * 16 + m16;
        float bxr = bx[j], bxi = bx[128 + j], bxn = bx[256 + j];
        float bhr = bh[j], bhi = bh[128 + j], bhn = bh[256 + j];
        #pragma unroll
        for (int mt = 0; mt < 4; ++mt) {
            #pragma unroll
            for (int ii = 0; ii < 4; ++ii) {
                int lrow = mt * 16 + g * 4 + ii;
                int grow = row0 + lrow;
                if (grow >= NN) continue;
                float rr = acc[0][mt][ii] + bxr + bhr;
                float ri = acc[1][mt][ii] + bxi + bhi;
                float rin = acc[2][mt][ii] + bxn;
                float rhn = bhn;
                float ho = 0.f;
                if (!FIRST) {
                    rhn += acc[3][mt][ii];
                    int sw = (j >> 3) ^ (lrow & 7);
                    int bi = (lrow * 16 + sw) * 8 + (j & 7);
                    ho = bf16_tf(sA[bi]) + bf16_tf(sA[64 * 128 + bi]);
                }
                float rg = sigmoid_f(rr);
                float ig = sigmoid_f(ri);
                float ng = tanh_f(rin + rg * rhn);
                float hy = ng + ig * (ho - ng);
                if (LAST) {
                    hout[(size_t)grow * 128 + j] = hy;
                } else {
                    unsigned short hh = bf16_rn(hy);
                    unsigned short hl = bf16_rn(hy - bf16_tf(hh));
                    Hpk[(size_t)grow * 128 + j] = (unsigned)hh | ((unsigned)hl << 16);
                }
            }
        }
    }
}

// LayerNorm
__global__ __launch_bounds__(256) void ln_kernel(float* __restrict__ h,
                                                 const float* __restrict__ g,
                                                 const float* __restrict__ b) {
    int tid = threadIdx.x;
    int lane = tid & 31;
    int rl = tid >> 5;
    int row = blockIdx.x * 8 + rl;
    if (row >= NN) return;
    float4 v = *reinterpret_cast<const float4*>(h + (size_t)row * DD + lane * 4);
    float s = v.x + v.y + v.z + v.w;
    #pragma unroll
    for (int m = 16; m >= 1; m >>= 1) s += __shfl_xor(s, m, 64);
    float mean = s * (1.0f / DD);
    float dx = v.x - mean, dy = v.y - mean, dz = v.z - mean, dw = v.w - mean;
    float q = dx * dx + dy * dy + dz * dz + dw * dw;
    #pragma unroll
    for (int m = 16; m >= 1; m >>= 1) q += __shfl_xor(q, m, 64);
    float var = q * (1.0f / DD);
    float inv = 1.0f / sqrtf(var + 1e-5f);
    float4 gv = *reinterpret_cast<const float4*>(g + lane * 4);
    float4 bv = *reinterpret_cast<const float4*>(b + lane * 4);
    float4 o;
    o.x = dx * inv * gv.x + bv.x;
    o.y = dy * inv * gv.y + bv.y;
    o.z = dz * inv * gv.z + bv.z;
    o.w = dw * inv * gv.w + bv.w;
    *reinterpret_cast<float4*>(h + (size_t)row * DD + lane * 4) = o;
}

static inline size_t align_up(size_t v, size_t a) { return (v + a - 1) & ~(a - 1); }

extern "C" void kernel_launch(void* const* d_in, const int* in_sizes, int n_in,
                              void* d_out, int out_size, void* d_ws, size_t ws_size,
                              hipStream_t stream) {
    const float* x    = (const float*)d_in[0];
    const float* vals = (const float*)d_in[1];
    const float* wx   = (const float*)d_in[2];
    const float* bx   = (const float*)d_in[3];
    const float* wh   = (const float*)d_in[4];
    const float* bh   = (const float*)d_in[5];
    const float* lng  = (const float*)d_in[6];
    const float* lnb  = (const float*)d_in[7];
    const int* rows   = (const int*)d_in[8];
    const int* cols   = (const int*)d_in[9];

    float* hout = (float*)d_out;

    size_t off = 0;
    char* wsb = (char*)d_ws;
    unsigned short* Rh = (unsigned short*)(wsb + off); off = align_up(off + (size_t)NN * DD * 2, 256);
    unsigned short* Rl = (unsigned short*)(wsb + off); off = align_up(off + (size_t)NN * DD * 2, 256);
    unsigned int* Hpk = (unsigned int*)(wsb + off);    off = align_up(off + (size_t)NN * DD * 4, 256);
    unsigned short* Wp = (unsigned short*)(wsb + off); off = align_up(off + (size_t)24 * 512 * 32 * 2, 256);
    int* row_ptr4 = (int*)(wsb + off);  off = align_up(off + (size_t)4 * (NN + 1) * 4, 256);
    int2* epair4 = (int2*)(wsb + off);  off = align_up(off + (size_t)4 * EE * 8, 256);
    int* bcnt4 = (int*)(wsb + off);     off = align_up(off + (size_t)4 * NBK * 4, 256);
    int* bbase4 = (int*)(wsb + off);    off = align_up(off + (size_t)4 * NBK * 4, 256);
    int* bcur4 = (int*)(wsb + off);     off = align_up(off + (size_t)4 * NBK * 4, 256);
    // staging aliases Rh/Rl (19.2 MB < 25.6 MB): CSR build completes before
    // the first gather writes Rh/Rl (stream-ordered)
    int2* st2 = (int2*)wsb;

    (void)in_sizes; (void)n_in; (void)out_size; (void)ws_size;

    pack_w_kernel<<<1536, 256, 0, stream>>>(wx, wh, Wp);

    hipMemsetAsync(bcnt4, 0, (size_t)4 * NBK * sizeof(int), stream);
    dim3 e2grid((EE + 2047) / 2048, 4);          // 293 x 4
    bhist_kernel<<<e2grid, 256, 0, stream>>>(rows, bcnt4);
    bscan_kernel<<<1, 64, 0, stream>>>(bcnt4, bbase4, bcur4);
    bscat_kernel<<<e2grid, 256, 0, stream>>>(rows, cols, vals, bcur4, st2);
    dim3 sgrid(NBK, 4);                          // 49 x 4
    sort2_kernel<<<sgrid, 1024, 0, stream>>>(st2, bbase4, bcnt4, row_ptr4, epair4);

    const int ggrid = NN / 8;                 // 6250
    const int mgrid = (NN + 63) / 64;         // 782

    for (int s = 0; s < 4; ++s) {
        int k = 3 - s;  // adj_list reversed
        gather_kernel<<<ggrid, 256, 0, stream>>>(
            x, row_ptr4 + (size_t)k * (NN + 1), epair4 + (size_t)k * EE, Rh, Rl);
        if (s == 0)
            gemm_gru_kernel<true, false><<<mgrid, 512, 0, stream>>>(
                Rh, Rl, Hpk, hout, Wp, bx, bh);
        else if (s < 3)
            gemm_gru_kernel<false, false><<<mgrid, 512, 0, stream>>>(
                Rh, Rl, Hpk, hout, Wp, bx, bh);
        else
            gemm_gru_kernel<false, true><<<mgrid, 512, 0, stream>>>(
                Rh, Rl, Hpk, hout, Wp, bx, bh);
    }

    ln_kernel<<<(NN + 7) / 8, 256, 0, stream>>>(hout, lng, lnb);
}

// Round 22
// 402.029 us; speedup vs baseline: 1.3382x; 1.0259x over previous
//
#include <hip/hip_runtime.h>
#include <cstdint>

#define NN 50000
#define DD 128
#define EE 600000
#define NBK 49          // row buckets of 1024
#define BCAP 14336      // sort2 LDS edge capacity (mean 12288, sigma~110)

typedef __attribute__((ext_vector_type(8))) short bf16x8;
typedef __attribute__((ext_vector_type(4))) float f32x4;

__device__ __forceinline__ float sigmoid_f(float x) {
    return 1.0f / (1.0f + __expf(-x));
}
__device__ __forceinline__ float tanh_f(float x) {
    float e = __expf(-2.0f * fabsf(x));
    float t = (1.0f - e) / (1.0f + e);
    return copysignf(t, x);
}
__device__ __forceinline__ unsigned short bf16_rn(float v) {
    unsigned u = __float_as_uint(v);
    u = u + 0x7fffu + ((u >> 16) & 1u);
    return (unsigned short)(u >> 16);
}
__device__ __forceinline__ float bf16_tf(unsigned short h) {
    return __uint_as_float(((unsigned)h) << 16);
}

// ---- weight packing into MFMA B-panels ------------------------------------
__global__ __launch_bounds__(256) void pack_w_kernel(const float* __restrict__ wx,
                                                     const float* __restrict__ wh,
                                                     unsigned short* __restrict__ Wp) {
    int idx = blockIdx.x * 256 + threadIdx.x;   // 24*512*32
    if (idx >= 24 * 512 * 32) return;
    int k8 = idx & 31;
    int n = (idx >> 5) & 511;
    int kb = idx >> 14;
    int grp = kb >> 2;
    int k = (kb & 3) * 32 + k8;
    float v = 0.f;
    if (grp < 3) {
        if (n < 384) v = wx[n * 128 + k];
    } else {
        if (n < 256) v = wh[n * 128 + k];
        else if (n >= 384) v = wh[(n - 128) * 128 + k];
    }
    unsigned short hi = bf16_rn(v);
    bool lo = (grp == 2) || (grp == 5);
    Wp[idx] = lo ? bf16_rn(v - bf16_tf(hi)) : hi;
}

// ---- CSR build ------------------------------------------------------------

__global__ __launch_bounds__(256) void bhist_kernel(const int* __restrict__ rows,
                                                    int* __restrict__ bcnt4) {
    __shared__ int lc[NBK];
    const int tid = threadIdx.x;
    const int k = blockIdx.y;
    const int e0 = blockIdx.x * 2048;
    if (tid < NBK) lc[tid] = 0;
    __syncthreads();
    #pragma unroll
    for (int i = 0; i < 8; ++i) {
        int e = e0 + i * 256 + tid;
        if (e < EE) atomicAdd(&lc[rows[(size_t)k * EE + e] >> 10], 1);
    }
    __syncthreads();
    if (tid < NBK && lc[tid]) atomicAdd(&bcnt4[k * NBK + tid], lc[tid]);
}

__global__ __launch_bounds__(64) void bscan_kernel(const int* __restrict__ bcnt4,
                                                   int* __restrict__ bbase4,
                                                   int* __restrict__ bcur4) {
    int k = threadIdx.x;
    if (k < 4) {
        int run = 0;
        for (int b = 0; b < NBK; ++b) {
            bbase4[k * NBK + b] = run;
            bcur4[k * NBK + b] = run;
            run += bcnt4[k * NBK + b];
        }
    }
}

__global__ __launch_bounds__(256) void bscat_kernel(const int* __restrict__ rows,
                                                    const int* __restrict__ cols,
                                                    const float* __restrict__ vals,
                                                    int* __restrict__ bcur4,
                                                    int2* __restrict__ st2) {
    __shared__ int lcnt[4][NBK];
    __shared__ int sstart4[4][NBK];
    __shared__ int sstart_b[NBK];
    __shared__ int gbase[NBK];
    __shared__ int ltot;
    __shared__ int sw0[2048];
    __shared__ int sw1[2048];
    __shared__ unsigned char sbk[2048];

    const int tid = threadIdx.x;
    const int w = tid >> 6;
    const int k = blockIdx.y;
    const int e0 = blockIdx.x * 2048;

    if (tid < NBK) { lcnt[0][tid] = 0; lcnt[1][tid] = 0; lcnt[2][tid] = 0; lcnt[3][tid] = 0; }
    __syncthreads();

    int eb[8], er[8], ew0[8], ew1[8];
    #pragma unroll
    for (int i = 0; i < 8; ++i) {
        int e = e0 + i * 256 + tid;
        eb[i] = -1;
        if (e < EE) {
            size_t off = (size_t)k * EE + e;
            int r = rows[off];
            int b = r >> 10;
            eb[i] = b;
            er[i] = atomicAdd(&lcnt[w][b], 1);
            ew0[i] = ((r & 1023) << 17) | cols[off];
            ew1[i] = __float_as_int(vals[off]);
        }
    }
    __syncthreads();
    if (tid == 0) {
        int run = 0;
        for (int b = 0; b < NBK; ++b) {
            sstart_b[b] = run;
            #pragma unroll
            for (int q = 0; q < 4; ++q) { sstart4[q][b] = run; run += lcnt[q][b]; }
        }
        ltot = run;
    }
    __syncthreads();
    if (tid < NBK) {
        int n = (sstart4[3][tid] + lcnt[3][tid]) - sstart_b[tid];
        if (n) gbase[tid] = atomicAdd(&bcur4[k * NBK + tid], n);
    }
    __syncthreads();
    #pragma unroll
    for (int i = 0; i < 8; ++i) {
        if (eb[i] >= 0) {
            int slot = sstart4[w][eb[i]] + er[i];
            sw0[slot] = ew0[i];
            sw1[slot] = ew1[i];
            sbk[slot] = (unsigned char)eb[i];
        }
    }
    __syncthreads();
    const int tot = ltot;
    #pragma unroll
    for (int i = 0; i < 8; ++i) {
        int slot = i * 256 + tid;
        if (slot < tot) {
            int b = sbk[slot];
            int pos = gbase[b] + (slot - sstart_b[b]);
            st2[(size_t)k * EE + pos] = make_int2(sw0[slot], sw1[slot]);
        }
    }
}

__global__ __launch_bounds__(1024, 1) void sort2_kernel(const int2* __restrict__ st2,
                                                        const int* __restrict__ bbase4,
                                                        const int* __restrict__ bcnt4,
                                                        int* __restrict__ row_ptr4,
                                                        int2* __restrict__ epair4) {
    __shared__ int cnt[1024];
    __shared__ int cur[1024];
    __shared__ int2 obuf[BCAP];

    const int tid = threadIdx.x;
    const int b = blockIdx.x;
    const int k = blockIdx.y;
    const int base = bbase4[k * NBK + b];
    const int n = bcnt4[k * NBK + b];

    cnt[tid] = 0;
    __syncthreads();
    for (int i = tid; i < n; i += 1024)
        atomicAdd(&cnt[st2[(size_t)k * EE + base + i].x >> 17], 1);
    __syncthreads();

    int v = cnt[tid];
    cur[tid] = v;
    __syncthreads();
    for (int d = 1; d < 1024; d <<= 1) {
        int t = (tid >= d) ? cur[tid - d] : 0;
        __syncthreads();
        cur[tid] += t;
        __syncthreads();
    }
    int excl = cur[tid] - v;

    int grow = b * 1024 + tid;
    if (grow <= NN) row_ptr4[k * (NN + 1) + grow] = base + excl;

    cur[tid] = excl;
    __syncthreads();
    for (int i = tid; i < n; i += 1024) {
        int2 p = st2[(size_t)k * EE + base + i];
        int rl = p.x >> 17;
        int pos = atomicAdd(&cur[rl], 1);
        if (pos < BCAP) obuf[pos] = make_int2(p.x & 0x1FFFF, p.y);
    }
    __syncthreads();
    for (int i = tid; i < n; i += 1024)
        epair4[(size_t)k * EE + base + i] = obuf[i];
}

// ---- FUSED SpMM + MFMA split-bf16 dual-GEMM + GRU --------------------------
// 512 thr = 8 waves; block owns 64 rows. SpMM (relu(A.x), split-bf16) is
// computed in-kernel directly into the LDS slabs (no Rh/Rl globals, no
// gather kernel, no 51.2MB round-trip). Then phase A kb 0-11, re-stage Hpk,
// phase B kb 12-23 (kq-major, hi-weight dedup -> L1). setprio around MFMA.
template <bool FIRST, bool LAST>
__global__ __launch_bounds__(512, 4)
void gemm_gru_kernel(const float* __restrict__ x,
                     const int* __restrict__ row_ptr,
                     const int2* __restrict__ epair,
                     unsigned int* __restrict__ Hpk,
                     float* __restrict__ hout,
                     const unsigned short* __restrict__ Wp,
                     const float* __restrict__ bx,
                     const float* __restrict__ bh) {
    __shared__ unsigned short sA[2 * 64 * 128];   // 32 KB (hi, lo slabs)

    const int tid = threadIdx.x;
    const int row0 = blockIdx.x * 64;
    const int lane = tid & 63;
    const int w = tid >> 6;        // 0..7
    const int g = lane >> 4;       // 0..3
    const int m16 = lane & 15;

    // ---- fused SpMM: 16 half-waves x 4 passes; 32 lanes/row, float4/lane
    {
        const int hw = tid >> 5;       // 0..15
        const int l32 = tid & 31;
        const int d0 = l32 * 4;
        #pragma unroll
        for (int p = 0; p < 4; ++p) {
            int rl = p * 16 + hw;
            int grow = row0 + rl;
            float4 a0 = make_float4(0.f, 0.f, 0.f, 0.f);
            float4 a1 = a0, a2 = a0, a3 = a0;
            if (grow < NN) {
                int start = row_ptr[grow];
                int end = row_ptr[grow + 1];
                int e = start;
                for (; e + 3 < end; e += 4) {
                    int2 p0 = epair[e], p1 = epair[e + 1], p2 = epair[e + 2], p3 = epair[e + 3];
                    float4 x0 = *reinterpret_cast<const float4*>(x + (size_t)p0.x * DD + d0);
                    float4 x1 = *reinterpret_cast<const float4*>(x + (size_t)p1.x * DD + d0);
                    float4 x2 = *reinterpret_cast<const float4*>(x + (size_t)p2.x * DD + d0);
                    float4 x3 = *reinterpret_cast<const float4*>(x + (size_t)p3.x * DD + d0);
                    float v0 = __int_as_float(p0.y), v1 = __int_as_float(p1.y);
                    float v2 = __int_as_float(p2.y), v3 = __int_as_float(p3.y);
                    a0.x += v0 * x0.x; a0.y += v0 * x0.y; a0.z += v0 * x0.z; a0.w += v0 * x0.w;
                    a1.x += v1 * x1.x; a1.y += v1 * x1.y; a1.z += v1 * x1.z; a1.w += v1 * x1.w;
                    a2.x += v2 * x2.x; a2.y += v2 * x2.y; a2.z += v2 * x2.z; a2.w += v2 * x2.w;
                    a3.x += v3 * x3.x; a3.y += v3 * x3.y; a3.z += v3 * x3.z; a3.w += v3 * x3.w;
                }
                for (; e < end; ++e) {
                    int2 p0 = epair[e];
                    float v0 = __int_as_float(p0.y);
                    float4 x0 = *reinterpret_cast<const float4*>(x + (size_t)p0.x * DD + d0);
                    a0.x += v0 * x0.x; a0.y += v0 * x0.y; a0.z += v0 * x0.z; a0.w += v0 * x0.w;
                }
            }
            float o[4];
            o[0] = fmaxf((a0.x + a1.x) + (a2.x + a3.x), 0.f);
            o[1] = fmaxf((a0.y + a1.y) + (a2.y + a3.y), 0.f);
            o[2] = fmaxf((a0.z + a1.z) + (a2.z + a3.z), 0.f);
            o[3] = fmaxf((a0.w + a1.w) + (a2.w + a3.w), 0.f);
            ushort4 vh, vl;
            unsigned short h0 = bf16_rn(o[0]); vh.x = h0; vl.x = bf16_rn(o[0] - bf16_tf(h0));
            unsigned short h1 = bf16_rn(o[1]); vh.y = h1; vl.y = bf16_rn(o[1] - bf16_tf(h1));
            unsigned short h2 = bf16_rn(o[2]); vh.z = h2; vl.z = bf16_rn(o[2] - bf16_tf(h2));
            unsigned short h3 = bf16_rn(o[3]); vh.w = h3; vl.w = bf16_rn(o[3] - bf16_tf(h3));
            int slot = l32 >> 1;                       // d0/8
            int sw = slot ^ (rl & 7);
            int bi = ((0 * 64 + rl) * 16 + sw) * 8 + (d0 & 7);
            *reinterpret_cast<ushort4*>(sA + bi) = vh;
            *reinterpret_cast<ushort4*>(sA + (64 * 128) + bi) = vl;
        }
    }
    __syncthreads();

    f32x4 acc[4][4];               // [gate][mt]
    #pragma unroll
    for (int G = 0; G < 4; ++G)
        #pragma unroll
        for (int mt = 0; mt < 4; ++mt)
            acc[G][mt] = (f32x4){0.f, 0.f, 0.f, 0.f};

    // stage B: packed Hpk -> de-interleave into hi/lo slabs
    auto stageH = [&]() {
        #pragma unroll
        for (int it = 0; it < 4; ++it) {
            int idx = it * 512 + tid;         // 0..2047
            int row = idx >> 5;               // 0..63
            int j0 = (idx & 31) * 4;
            int grow = row0 + row;
            uint4 v = make_uint4(0, 0, 0, 0);
            if (grow < NN)
                v = *reinterpret_cast<const uint4*>(Hpk + (size_t)grow * 128 + j0);
            ushort4 hh = make_ushort4(v.x & 0xFFFF, v.y & 0xFFFF, v.z & 0xFFFF, v.w & 0xFFFF);
            ushort4 hl = make_ushort4(v.x >> 16, v.y >> 16, v.z >> 16, v.w >> 16);
            int sw = (j0 >> 3) ^ (row & 7);
            int b0 = ((0 * 64 + row) * 16 + sw) * 8 + (j0 & 7);
            int b1 = ((1 * 64 + row) * 16 + sw) * 8 + (j0 & 7);
            *reinterpret_cast<ushort4*>(sA + b0) = hh;
            *reinterpret_cast<ushort4*>(sA + b1) = hl;
        }
    };

    // one 12-MFMA cluster: B from panel kbW, A from slab arr at k-quad kq
    auto do_kb2 = [&](int kbW, int kq, int arr, int G0, int G1, int G2) {
        bf16x8 bfr[3];
        const int Gs[3] = {G0, G1, G2};
        #pragma unroll
        for (int i = 0; i < 3; ++i) {
            int n = Gs[i] * 128 + w * 16 + m16;
            bfr[i] = *reinterpret_cast<const bf16x8*>(
                Wp + ((size_t)(kbW * 512 + n)) * 32 + g * 8);
        }
        bf16x8 afr[4];
        #pragma unroll
        for (int mt = 0; mt < 4; ++mt) {
            int row = mt * 16 + m16;
            int sw = (kq * 4 + g) ^ (row & 7);
            afr[mt] = *reinterpret_cast<const bf16x8*>(
                sA + ((arr * 64 + row) * 16 + sw) * 8);
        }
        __builtin_amdgcn_s_setprio(1);
        #pragma unroll
        for (int mt = 0; mt < 4; ++mt) {
            acc[G0][mt] = __builtin_amdgcn_mfma_f32_16x16x32_bf16(afr[mt], bfr[0], acc[G0][mt], 0, 0, 0);
            acc[G1][mt] = __builtin_amdgcn_mfma_f32_16x16x32_bf16(afr[mt], bfr[1], acc[G1][mt], 0, 0, 0);
            acc[G2][mt] = __builtin_amdgcn_mfma_f32_16x16x32_bf16(afr[mt], bfr[2], acc[G2][mt], 0, 0, 0);
        }
        __builtin_amdgcn_s_setprio(0);
    };

    // phase A: x-side, kq-major; Whi panel reused (2nd use hits L1)
    for (int kq = 0; kq < 4; ++kq) {
        do_kb2(kq,     kq, 0, 0, 1, 2);   // Rh x Whi
        do_kb2(kq,     kq, 1, 0, 1, 2);   // Rl x Whi (L1 hit)
        do_kb2(8 + kq, kq, 0, 0, 1, 2);   // Rh x Wlo
    }

    // phase B: h-side
    if (!FIRST) {
        __syncthreads();
        stageH();
        __syncthreads();
        for (int kq = 0; kq < 4; ++kq) {
            do_kb2(12 + kq, kq, 0, 0, 1, 3);   // Hh x Whi_h
            do_kb2(12 + kq, kq, 1, 0, 1, 3);   // Hl x Whi_h (L1 hit)
            do_kb2(20 + kq, kq, 0, 0, 1, 3);   // Hh x Wlo_h
        }
    }

    // ---- GRU epilogue: C layout col=m16, row=g*4+ii (m89)
    {
        int j = w * 16 + m16;
        float bxr = bx[j], bxi = bx[128 + j], bxn = bx[256 + j];
        float bhr = bh[j], bhi = bh[128 + j], bhn = bh[256 + j];
        #pragma unroll
        for (int mt = 0; mt < 4; ++mt) {
            #pragma unroll
            for (int ii = 0; ii < 4; ++ii) {
                int lrow = mt * 16 + g * 4 + ii;
                int grow = row0 + lrow;
                if (grow >= NN) continue;
                float rr = acc[0][mt][ii] + bxr + bhr;
                float ri = acc[1][mt][ii] + bxi + bhi;
                float rin = acc[2][mt][ii] + bxn;
                float rhn = bhn;
                float ho = 0.f;
                if (!FIRST) {
                    rhn += acc[3][mt][ii];
                    int sw = (j >> 3) ^ (lrow & 7);
                    int bi = (lrow * 16 + sw) * 8 + (j & 7);
                    ho = bf16_tf(sA[bi]) + bf16_tf(sA[64 * 128 + bi]);
                }
                float rg = sigmoid_f(rr);
                float ig = sigmoid_f(ri);
                float ng = tanh_f(rin + rg * rhn);
                float hy = ng + ig * (ho - ng);
                if (LAST) {
                    hout[(size_t)grow * 128 + j] = hy;
                } else {
                    unsigned short hh = bf16_rn(hy);
                    unsigned short hl = bf16_rn(hy - bf16_tf(hh));
                    Hpk[(size_t)grow * 128 + j] = (unsigned)hh | ((unsigned)hl << 16);
                }
            }
        }
    }
}

// LayerNorm
__global__ __launch_bounds__(256) void ln_kernel(float* __restrict__ h,
                                                 const float* __restrict__ g,
                                                 const float* __restrict__ b) {
    int tid = threadIdx.x;
    int lane = tid & 31;
    int rl = tid >> 5;
    int row = blockIdx.x * 8 + rl;
    if (row >= NN) return;
    float4 v = *reinterpret_cast<const float4*>(h + (size_t)row * DD + lane * 4);
    float s = v.x + v.y + v.z + v.w;
    #pragma unroll
    for (int m = 16; m >= 1; m >>= 1) s += __shfl_xor(s, m, 64);
    float mean = s * (1.0f / DD);
    float dx = v.x - mean, dy = v.y - mean, dz = v.z - mean, dw = v.w - mean;
    float q = dx * dx + dy * dy + dz * dz + dw * dw;
    #pragma unroll
    for (int m = 16; m >= 1; m >>= 1) q += __shfl_xor(q, m, 64);
    float var = q * (1.0f / DD);
    float inv = 1.0f / sqrtf(var + 1e-5f);
    float4 gv = *reinterpret_cast<const float4*>(g + lane * 4);
    float4 bv = *reinterpret_cast<const float4*>(b + lane * 4);
    float4 o;
    o.x = dx * inv * gv.x + bv.x;
    o.y = dy * inv * gv.y + bv.y;
    o.z = dz * inv * gv.z + bv.z;
    o.w = dw * inv * gv.w + bv.w;
    *reinterpret_cast<float4*>(h + (size_t)row * DD + lane * 4) = o;
}

static inline size_t align_up(size_t v, size_t a) { return (v + a - 1) & ~(a - 1); }

extern "C" void kernel_launch(void* const* d_in, const int* in_sizes, int n_in,
                              void* d_out, int out_size, void* d_ws, size_t ws_size,
                              hipStream_t stream) {
    const float* x    = (const float*)d_in[0];
    const float* vals = (const float*)d_in[1];
    const float* wx   = (const float*)d_in[2];
    const float* bx   = (const float*)d_in[3];
    const float* wh   = (const float*)d_in[4];
    const float* bh   = (const float*)d_in[5];
    const float* lng  = (const float*)d_in[6];
    const float* lnb  = (const float*)d_in[7];
    const int* rows   = (const int*)d_in[8];
    const int* cols   = (const int*)d_in[9];

    float* hout = (float*)d_out;

    size_t off = 0;
    char* wsb = (char*)d_ws;
    int2* st2 = (int2*)(wsb + off);     off = align_up(off + (size_t)4 * EE * 8, 256);
    unsigned int* Hpk = (unsigned int*)(wsb + off);    off = align_up(off + (size_t)NN * DD * 4, 256);
    unsigned short* Wp = (unsigned short*)(wsb + off); off = align_up(off + (size_t)24 * 512 * 32 * 2, 256);
    int* row_ptr4 = (int*)(wsb + off);  off = align_up(off + (size_t)4 * (NN + 1) * 4, 256);
    int2* epair4 = (int2*)(wsb + off);  off = align_up(off + (size_t)4 * EE * 8, 256);
    int* bcnt4 = (int*)(wsb + off);     off = align_up(off + (size_t)4 * NBK * 4, 256);
    int* bbase4 = (int*)(wsb + off);    off = align_up(off + (size_t)4 * NBK * 4, 256);
    int* bcur4 = (int*)(wsb + off);     off = align_up(off + (size_t)4 * NBK * 4, 256);

    (void)in_sizes; (void)n_in; (void)out_size; (void)ws_size;

    pack_w_kernel<<<1536, 256, 0, stream>>>(wx, wh, Wp);

    hipMemsetAsync(bcnt4, 0, (size_t)4 * NBK * sizeof(int), stream);
    dim3 e2grid((EE + 2047) / 2048, 4);          // 293 x 4
    bhist_kernel<<<e2grid, 256, 0, stream>>>(rows, bcnt4);
    bscan_kernel<<<1, 64, 0, stream>>>(bcnt4, bbase4, bcur4);
    bscat_kernel<<<e2grid, 256, 0, stream>>>(rows, cols, vals, bcur4, st2);
    dim3 sgrid(NBK, 4);                          // 49 x 4
    sort2_kernel<<<sgrid, 1024, 0, stream>>>(st2, bbase4, bcnt4, row_ptr4, epair4);

    const int mgrid = (NN + 63) / 64;         // 782

    for (int s = 0; s < 4; ++s) {
        int k = 3 - s;  // adj_list reversed
        const int* rp = row_ptr4 + (size_t)k * (NN + 1);
        const int2* ep = epair4 + (size_t)k * EE;
        if (s == 0)
            gemm_gru_kernel<true, false><<<mgrid, 512, 0, stream>>>(
                x, rp, ep, Hpk, hout, Wp, bx, bh);
        else if (s < 3)
            gemm_gru_kernel<false, false><<<mgrid, 512, 0, stream>>>(
                x, rp, ep, Hpk, hout, Wp, bx, bh);
        else
            gemm_gru_kernel<false, true><<<mgrid, 512, 0, stream>>>(
                x, rp, ep, Hpk, hout, Wp, bx, bh);
    }

    ln_kernel<<<(NN + 7) / 8, 256, 0, stream>>>(hout, lng, lnb);
}